// Round 5
// baseline (473.989 us; speedup 1.0000x reference)
//
#include <hip/hip_runtime.h>

#define T 2048
#define SD 1024
#define ED 1024
#define HID 150
#define MAXW 10

typedef float f32x4 __attribute__((ext_vector_type(4)));

// ---------------------------------------------------------------------------
// Kernel 1: per-token MLP score -> stores exp(score) (softmax numerator).
// EXACT R0 version (known-good): 4 tokens/block, 256 threads, w1 row-pairs
// register double-buffered.
// ---------------------------------------------------------------------------
__global__ __launch_bounds__(256) void mlp_scores_kernel(
    const float* __restrict__ states,
    const float* __restrict__ w1, const float* __restrict__ b1,
    const float* __restrict__ w2, const float* __restrict__ b2,
    const float* __restrict__ w3, const float* __restrict__ b3,
    float* __restrict__ expA)
{
    const int t0 = blockIdx.x * 4;
    __shared__ float4 s_state[4][256];
    __shared__ float s_h1[4][192];   // padded to 192, zero-filled tail
    __shared__ float s_h2[4][192];
    const int tid = threadIdx.x;

    for (int i = tid; i < 4 * 192; i += 256) {
        (&s_h1[0][0])[i] = 0.f;
        (&s_h2[0][0])[i] = 0.f;
    }
    {
        const float4* src = (const float4*)(states + (size_t)t0 * SD);
        float4* dst = &s_state[0][0];
        for (int i = tid; i < 4 * SD / 4; i += 256) dst[i] = src[i];
    }
    __syncthreads();

    const int lane = tid & 63;
    const int wave = tid >> 6;

    // ---- layer 1: h1 = relu(states @ w1^T + b1), j-pairs, double-buffered ----
    {
        int j = wave * 2;
        float4 wra[4], wrb[4];
        {
            const float4* w4a = (const float4*)(w1 + (size_t)j * SD);
#pragma unroll
            for (int m = 0; m < 4; ++m) {
                wra[m] = w4a[m * 64 + lane];
                wrb[m] = w4a[256 + m * 64 + lane];
            }
        }
        while (j < HID) {
            const int jn = j + 8;
            const int jp = (jn < HID) ? jn : j;   // clamp: last iter reloads self
            float4 nra[4], nrb[4];
            {
                const float4* n4a = (const float4*)(w1 + (size_t)jp * SD);
#pragma unroll
                for (int m = 0; m < 4; ++m) {      // prefetch BEFORE compute
                    nra[m] = n4a[m * 64 + lane];
                    nrb[m] = n4a[256 + m * 64 + lane];
                }
            }
            const float bja = b1[j];
            const float bjb = b1[j + 1];
#pragma unroll
            for (int t = 0; t < 4; ++t) {
                float acc0 = 0.f, acc1 = 0.f;
#pragma unroll
                for (int m = 0; m < 4; ++m) {
                    const float4 sv = s_state[t][m * 64 + lane];  // ds_read_b128
                    acc0 += sv.x * wra[m].x + sv.y * wra[m].y
                          + sv.z * wra[m].z + sv.w * wra[m].w;
                    acc1 += sv.x * wrb[m].x + sv.y * wrb[m].y
                          + sv.z * wrb[m].z + sv.w * wrb[m].w;
                }
#pragma unroll
                for (int off = 32; off > 0; off >>= 1) {
                    acc0 += __shfl_down(acc0, off, 64);
                    acc1 += __shfl_down(acc1, off, 64);
                }
                if (lane == 0) {
                    s_h1[t][j]     = fmaxf(acc0 + bja, 0.f);
                    s_h1[t][j + 1] = fmaxf(acc1 + bjb, 0.f);
                }
            }
#pragma unroll
            for (int m = 0; m < 4; ++m) { wra[m] = nra[m]; wrb[m] = nrb[m]; }
            j = jn;
        }
    }
    __syncthreads();

    // ---- layer 2: h2 = relu(h1 @ w2^T + b2) ----
    for (int j = wave; j < HID; j += 4) {
        const float* wrow = w2 + (size_t)j * HID;
        const float wa = wrow[lane];
        const float wb = wrow[lane + 64];
        const float wc = (lane + 128 < HID) ? wrow[lane + 128] : 0.f;
        const float bj = b2[j];
#pragma unroll
        for (int t = 0; t < 4; ++t) {
            float acc = s_h1[t][lane] * wa + s_h1[t][lane + 64] * wb
                      + s_h1[t][lane + 128] * wc;
#pragma unroll
            for (int off = 32; off > 0; off >>= 1) acc += __shfl_down(acc, off, 64);
            if (lane == 0) s_h2[t][j] = fmaxf(acc + bj, 0.f);
        }
    }
    __syncthreads();

    // ---- layer 3: scalar score; wave t handles token t ----
    {
        const int t = wave;
        const float wa = w3[lane];
        const float wb = w3[lane + 64];
        const float wc = (lane + 128 < HID) ? w3[lane + 128] : 0.f;
        float acc = s_h2[t][lane] * wa + s_h2[t][lane + 64] * wb
                  + s_h2[t][lane + 128] * wc;
#pragma unroll
        for (int off = 32; off > 0; off >>= 1) acc += __shfl_down(acc, off, 64);
        if (lane == 0) expA[t0 + t] = expf(acc + b3[0]);
    }
}

// ---------------------------------------------------------------------------
// Kernel 2: EXACT R0 champion version (start-major, all 21 loads upfront,
// plain stores — 358.1 us total, best of all variants tried).
//
// MEASUREMENT ROUND: this kernel is launched 3x (idempotent — deterministic
// pure function of its inputs, so repeated stores write identical values).
// dur_us - 358 ~= 2 x span_warm. The top-5 profile table is saturated by
// ~155 us harness fills, so span has never been directly observed; this
// round turns the wall timer into a probe to decide between
//   world A: span ~150 us (1.8 TB/s, ~100 us winnable)
//   world B: span ~50 us (near write roofline, slack is harness overhead)
// ---------------------------------------------------------------------------
__global__ __launch_bounds__(256) void span_kernel(
    const float* __restrict__ embeds,
    const float* __restrict__ states,
    const float* __restrict__ expA,
    float* __restrict__ out)
{
    const int s = blockIdx.x;
    const int c = threadIdx.x;  // float4 index within a 1024-float segment

    const f32x4 st_s = ((const f32x4*)(states + (size_t)s * SD))[c];

    f32x4 P = (f32x4)(0.f);
    float S = 0.f;

    if (s <= T - MAXW) {
        int base = 0;
#pragma unroll
        for (int i = 0; i < MAXW; ++i) {
            const float E = expA[s + i];
            const f32x4 e  = ((const f32x4*)(embeds + (size_t)(s + i) * ED))[c];
            const f32x4 se = ((const f32x4*)(states + (size_t)(s + i) * SD))[c];
            P += E * e;
            S += E;
            const float inv = 1.f / S;
            f32x4* orow = (f32x4*)(out + (size_t)(base + s) * 3072);
            orow[c]       = st_s;
            orow[256 + c] = se;
            orow[512 + c] = P * inv;
            base += T - i;
        }
    } else {
        int base = 0;
        for (int i = 0; i < MAXW; ++i) {
            if (s + i < T) {
                const float E = expA[s + i];
                const f32x4 e  = ((const f32x4*)(embeds + (size_t)(s + i) * ED))[c];
                const f32x4 se = ((const f32x4*)(states + (size_t)(s + i) * SD))[c];
                P += E * e;
                S += E;
                const float inv = 1.f / S;
                f32x4* orow = (f32x4*)(out + (size_t)(base + s) * 3072);
                orow[c]       = st_s;
                orow[256 + c] = se;
                orow[512 + c] = P * inv;
            }
            base += T - i;
        }
    }
}

extern "C" void kernel_launch(void* const* d_in, const int* in_sizes, int n_in,
                              void* d_out, int out_size, void* d_ws, size_t ws_size,
                              hipStream_t stream) {
    const float* embeds = (const float*)d_in[0];
    const float* states = (const float*)d_in[1];
    const float* w1 = (const float*)d_in[2];
    const float* b1 = (const float*)d_in[3];
    const float* w2 = (const float*)d_in[4];
    const float* b2 = (const float*)d_in[5];
    const float* w3 = (const float*)d_in[6];
    const float* b3 = (const float*)d_in[7];
    float* out = (float*)d_out;
    float* expA = (float*)d_ws;  // T floats of scratch

    mlp_scores_kernel<<<T / 4, 256, 0, stream>>>(states, w1, b1, w2, b2, w3, b3, expA);
    // 3x launch: spans 2 and 3 are redundant but idempotent; their combined
    // extra time (= 2 x span duration) is read off the harness wall clock.
    span_kernel<<<T, 256, 0, stream>>>(embeds, states, expA, out);
    span_kernel<<<T, 256, 0, stream>>>(embeds, states, expA, out);
    span_kernel<<<T, 256, 0, stream>>>(embeds, states, expA, out);
}